// Round 1
// baseline (250.236 us; speedup 1.0000x reference)
//
#include <hip/hip_runtime.h>
#include <hip/hip_bf16.h>

// Isokawa quaternion layer as bf16-MFMA GEMM:
//   out[b, n*4+oc] = sigmoid( sum_k x[b,k] * C[k, n*4+oc] - theta[n*4+oc] )
// where k = m*4+ic and C is built from W via the Hamilton product table.
//
// B=131072 rows, K=256, N=256. Memory-bound: 134 MB in + 134 MB out.

typedef __bf16 bf16_t;
typedef bf16_t bf16x8 __attribute__((ext_vector_type(8)));
typedef bf16_t bf16x4v __attribute__((ext_vector_type(4)));
typedef float f32x4 __attribute__((ext_vector_type(4)));

#define B_TOTAL 131072
#define KDIM 256
#define NDIM 256
#define ROWS 64          // batch rows per block
#define THREADS 512      // 8 waves
#define LDS_STRIDE 264   // bf16 elems per row: 256 + 8 pad (16B-aligned rows, bank rotate)

// ---------------------------------------------------------------------------
// Kernel 1: build coefficient matrix in MFMA B-fragment order (bf16, in d_ws).
// Fragment layout consumed by main kernel:
//   coef_frag[((ntile*8 + ks)*64 + lane)*8 + j] = Bmat[k][col]
//     col = ntile*16 + (lane&15),  k = ks*32 + (lane>>4)*8 + j
// Bmat[k][col]: col = n*4+oc, k = m*4+ic,
//   value = sign[oc][ic] * W[n, m, widx[oc][ic]]
// Hamilton table (W on the left, s = sum_m W (x) x):
//   oc=0: [ww+, wx-, wy-, wz-]
//   oc=1: [wx+, ww+, wz-, wy+]
//   oc=2: [wy+, wz+, ww+, wx-]
//   oc=3: [wz+, wy-, wx+, ww+]
// ---------------------------------------------------------------------------
__global__ void coef_kernel(const float* __restrict__ W, bf16_t* __restrict__ coef) {
    const int widx[4][4] = {{0,1,2,3},{1,0,3,2},{2,3,0,1},{3,2,1,0}};
    const float sgn[4][4] = {{1.f,-1.f,-1.f,-1.f},
                             {1.f, 1.f,-1.f, 1.f},
                             {1.f, 1.f, 1.f,-1.f},
                             {1.f,-1.f, 1.f, 1.f}};
    int g = blockIdx.x * blockDim.x + threadIdx.x;   // 0..16383
#pragma unroll
    for (int e = 0; e < 4; e++) {
        int F = g * 4 + e;                           // 0..65535
        int j    = F & 7;
        int lane = (F >> 3) & 63;
        int ks   = (F >> 9) & 7;
        int nt   = F >> 12;
        int col  = nt * 16 + (lane & 15);
        int k    = ks * 32 + (lane >> 4) * 8 + j;
        int n = col >> 2, oc = col & 3;
        int m = k >> 2,   ic = k & 3;
        float v = sgn[oc][ic] * W[n * 256 + m * 4 + widx[oc][ic]];
        coef[F] = (bf16_t)v;
    }
}

// ---------------------------------------------------------------------------
// Kernel 2: main GEMM. Block = 64 rows x 256 cols. 8 waves; wave w:
//   rows [ (w>>2)*32, +32 ), cols [ (w&3)*64, +64 )  -> 2x4 tiles of 16x16.
// MFMA 16x16x32 bf16 fragment layouts (m89/m120-verified):
//   A: lane holds A[m=lane&15][k=(lane>>4)*8 + j]
//   B: lane holds B[k=(lane>>4)*8 + j][n=lane&15]
//   C/D: col=lane&15, row=(lane>>4)*4 + reg
// ---------------------------------------------------------------------------
__global__ __launch_bounds__(THREADS, 4)
void main_kernel(const float* __restrict__ x, const bf16x8* __restrict__ coef,
                 const float* __restrict__ theta, float* __restrict__ out) {
    __shared__ __align__(16) bf16_t xs[ROWS * LDS_STRIDE];

    const int tid  = threadIdx.x;
    const int tile = blockIdx.x;
    const int row0 = tile * ROWS;

    // --- stage x tile: 64 rows x 256 fp32 -> bf16 LDS, coalesced float4 loads
    const float4* xp = (const float4*)(x + (long)row0 * KDIM);
    float4 v[8];
#pragma unroll
    for (int i = 0; i < 8; i++) v[i] = xp[tid + THREADS * i];
#pragma unroll
    for (int i = 0; i < 8; i++) {
        int f = tid + THREADS * i;          // float4 index in tile
        int r = f >> 6;                     // row (64 float4 per row)
        int c = (f & 63) * 4;               // k offset
        bf16x4v w;
        w.x = (bf16_t)v[i].x; w.y = (bf16_t)v[i].y;
        w.z = (bf16_t)v[i].z; w.w = (bf16_t)v[i].w;
        *(bf16x4v*)&xs[r * LDS_STRIDE + c] = w;
    }
    __syncthreads();

    const int wave = tid >> 6, lane = tid & 63;
    const int colq = wave & 3, rowh = wave >> 2;
    const int l15  = lane & 15, quad = lane >> 4;

    // theta per col-tile (col = colq*64 + ct*16 + l15)
    float th[4];
#pragma unroll
    for (int ct = 0; ct < 4; ct++) th[ct] = theta[colq * 64 + ct * 16 + l15];

    f32x4 acc[2][4];
#pragma unroll
    for (int rt = 0; rt < 2; rt++)
#pragma unroll
        for (int ct = 0; ct < 4; ct++) acc[rt][ct] = (f32x4)(0.f);

#pragma unroll 2
    for (int ks = 0; ks < 8; ks++) {
        bf16x8 a[2], b[4];
#pragma unroll
        for (int rt = 0; rt < 2; rt++) {
            int r = rowh * 32 + rt * 16 + l15;
            a[rt] = *(const bf16x8*)&xs[r * LDS_STRIDE + ks * 32 + quad * 8];
        }
#pragma unroll
        for (int ct = 0; ct < 4; ct++) {
            int nt = colq * 4 + ct;
            b[ct] = coef[(nt * 8 + ks) * 64 + lane];
        }
#pragma unroll
        for (int rt = 0; rt < 2; rt++)
#pragma unroll
            for (int ct = 0; ct < 4; ct++)
                acc[rt][ct] = __builtin_amdgcn_mfma_f32_16x16x32_bf16(
                    a[rt], b[ct], acc[rt][ct], 0, 0, 0);
    }

    // --- epilogue: bias + sigmoid, direct stores (64B segments, merged in L2)
#pragma unroll
    for (int rt = 0; rt < 2; rt++) {
        int rbase = row0 + rowh * 32 + rt * 16 + quad * 4;
#pragma unroll
        for (int ct = 0; ct < 4; ct++) {
            int col = colq * 64 + ct * 16 + l15;
#pragma unroll
            for (int r = 0; r < 4; r++) {
                float s = acc[rt][ct][r] - th[ct];
                float y = 1.0f / (1.0f + __expf(-s));
                out[(long)(rbase + r) * NDIM + col] = y;
            }
        }
    }
}

extern "C" void kernel_launch(void* const* d_in, const int* in_sizes, int n_in,
                              void* d_out, int out_size, void* d_ws, size_t ws_size,
                              hipStream_t stream) {
    const float* x     = (const float*)d_in[0];   // (131072, 64, 4) fp32
    const float* W     = (const float*)d_in[1];   // (64, 64, 4) fp32
    const float* theta = (const float*)d_in[2];   // (64, 4) fp32
    float* out = (float*)d_out;                   // (131072, 64, 4) fp32
    bf16_t* coef = (bf16_t*)d_ws;                 // 65536 bf16 = 128 KB

    if (ws_size < 65536 * sizeof(bf16_t)) return; // ws too small -> visible failure

    coef_kernel<<<64, 256, 0, stream>>>(W, coef);
    main_kernel<<<B_TOTAL / ROWS, THREADS, 0, stream>>>(
        x, (const bf16x8*)coef, theta, out);
}

// Round 2
// 242.882 us; speedup vs baseline: 1.0303x; 1.0303x over previous
//
#include <hip/hip_runtime.h>
#include <hip/hip_bf16.h>

// Isokawa quaternion layer as bf16-MFMA GEMM:
//   out[b, n*4+oc] = sigmoid( sum_k x[b,k] * C[k, n*4+oc] - theta[n*4+oc] )
// B=131072 rows, K=256, N=256. Memory-bound: 134 MB in + 134 MB out.
//
// R2: B-matrix fragments live entirely in registers (prefetched before the
// barrier); K-loop is ds_read + MFMA only. Wave tile = 64 rows x 32 cols
// so B regs = 16 frags = 64 VGPR.

typedef __bf16 bf16_t;
typedef bf16_t bf16x8 __attribute__((ext_vector_type(8)));
typedef bf16_t bf16x4v __attribute__((ext_vector_type(4)));
typedef float f32x4 __attribute__((ext_vector_type(4)));

#define B_TOTAL 131072
#define KDIM 256
#define NDIM 256
#define ROWS 64          // batch rows per block
#define THREADS 512      // 8 waves; wave w owns cols [w*32, w*32+32)
#define LDS_STRIDE 264   // bf16 elems per row: 256 + 8 pad

// ---------------------------------------------------------------------------
// Kernel 1: build coefficient matrix in MFMA B-fragment order (bf16, in d_ws).
//   coef_frag[((nt*8 + ks)*64 + lane)*8 + j] = Bmat[k][col]
//     col = nt*16 + (lane&15),  k = ks*32 + (lane>>4)*8 + j
// Bmat[k][col]: col = n*4+oc, k = m*4+ic,
//   value = sign[oc][ic] * W[n, m, widx[oc][ic]]  (Hamilton, W on the left)
// ---------------------------------------------------------------------------
__global__ void coef_kernel(const float* __restrict__ W, bf16_t* __restrict__ coef) {
    const int widx[4][4] = {{0,1,2,3},{1,0,3,2},{2,3,0,1},{3,2,1,0}};
    const float sgn[4][4] = {{1.f,-1.f,-1.f,-1.f},
                             {1.f, 1.f,-1.f, 1.f},
                             {1.f, 1.f, 1.f,-1.f},
                             {1.f,-1.f, 1.f, 1.f}};
    int F = blockIdx.x * blockDim.x + threadIdx.x;   // 0..65535, one elem each
    int j    = F & 7;
    int lane = (F >> 3) & 63;
    int ks   = (F >> 9) & 7;
    int nt   = F >> 12;
    int col  = nt * 16 + (lane & 15);
    int k    = ks * 32 + (lane >> 4) * 8 + j;
    int n = col >> 2, oc = col & 3;
    int m = k >> 2,   ic = k & 3;
    coef[F] = (bf16_t)(sgn[oc][ic] * W[n * 256 + m * 4 + widx[oc][ic]]);
}

// ---------------------------------------------------------------------------
// Kernel 2: main GEMM. Block = 64 rows x 256 cols; 8 waves.
// Wave w: all 64 rows (rt=0..3), cols [w*32, +32) (ct=0..1, nt=w*2+ct).
// MFMA 16x16x32 bf16 layouts (m89/m120-verified):
//   A: lane holds A[m=lane&15][k=(lane>>4)*8 + j]
//   B: lane holds B[k=(lane>>4)*8 + j][n=lane&15]
//   C/D: col=lane&15, row=(lane>>4)*4 + reg
// ---------------------------------------------------------------------------
__global__ __launch_bounds__(THREADS, 4)
void main_kernel(const float* __restrict__ x, const bf16x8* __restrict__ coef,
                 const float* __restrict__ theta, float* __restrict__ out) {
    __shared__ __align__(16) bf16_t xs[ROWS * LDS_STRIDE];

    const int tid  = threadIdx.x;
    const int row0 = blockIdx.x * ROWS;
    const int wave = tid >> 6, lane = tid & 63;
    const int l15  = lane & 15, quad = lane >> 4;

    // --- issue x loads FIRST (HBM, longest latency), coalesced float4
    const float4* xp = (const float4*)(x + (long)row0 * KDIM);
    float4 v[8];
#pragma unroll
    for (int i = 0; i < 8; i++) v[i] = xp[tid + THREADS * i];

    // --- prefetch this wave's entire B slice into registers (L2 hits)
    bf16x8 breg[2][8];
#pragma unroll
    for (int ct = 0; ct < 2; ct++)
#pragma unroll
        for (int ks = 0; ks < 8; ks++)
            breg[ct][ks] = coef[((wave * 2 + ct) * 8 + ks) * 64 + lane];

    // --- stage x tile fp32 -> bf16 into LDS
#pragma unroll
    for (int i = 0; i < 8; i++) {
        int f = tid + THREADS * i;          // float4 index in 64x256 tile
        int r = f >> 6;                     // row (64 float4 per row)
        int c = (f & 63) * 4;               // k offset
        bf16x4v w;
        w.x = (bf16_t)v[i].x; w.y = (bf16_t)v[i].y;
        w.z = (bf16_t)v[i].z; w.w = (bf16_t)v[i].w;
        *(bf16x4v*)&xs[r * LDS_STRIDE + c] = w;
    }
    __syncthreads();

    f32x4 acc[4][2];
#pragma unroll
    for (int rt = 0; rt < 4; rt++)
#pragma unroll
        for (int ct = 0; ct < 2; ct++) acc[rt][ct] = (f32x4)(0.f);

    // --- K-loop: pure LDS reads + MFMA, fully unrolled
#pragma unroll
    for (int ks = 0; ks < 8; ks++) {
        bf16x8 a[4];
#pragma unroll
        for (int rt = 0; rt < 4; rt++)
            a[rt] = *(const bf16x8*)&xs[(rt * 16 + l15) * LDS_STRIDE + ks * 32 + quad * 8];
#pragma unroll
        for (int rt = 0; rt < 4; rt++)
#pragma unroll
            for (int ct = 0; ct < 2; ct++)
                acc[rt][ct] = __builtin_amdgcn_mfma_f32_16x16x32_bf16(
                    a[rt], breg[ct][ks], acc[rt][ct], 0, 0, 0);
    }

    // --- epilogue: bias + sigmoid, direct stores
    float th[2];
#pragma unroll
    for (int ct = 0; ct < 2; ct++) th[ct] = theta[wave * 32 + ct * 16 + l15];

#pragma unroll
    for (int rt = 0; rt < 4; rt++) {
        int rbase = row0 + rt * 16 + quad * 4;
#pragma unroll
        for (int ct = 0; ct < 2; ct++) {
            int col = wave * 32 + ct * 16 + l15;
#pragma unroll
            for (int r = 0; r < 4; r++) {
                float s = acc[rt][ct][r] - th[ct];
                float y = 1.0f / (1.0f + __expf(-s));
                out[(long)(rbase + r) * NDIM + col] = y;
            }
        }
    }
}

extern "C" void kernel_launch(void* const* d_in, const int* in_sizes, int n_in,
                              void* d_out, int out_size, void* d_ws, size_t ws_size,
                              hipStream_t stream) {
    const float* x     = (const float*)d_in[0];   // (131072, 64, 4) fp32
    const float* W     = (const float*)d_in[1];   // (64, 64, 4) fp32
    const float* theta = (const float*)d_in[2];   // (64, 4) fp32
    float* out = (float*)d_out;                   // (131072, 64, 4) fp32
    bf16_t* coef = (bf16_t*)d_ws;                 // 65536 bf16 = 128 KB

    if (ws_size < 65536 * sizeof(bf16_t)) return;

    coef_kernel<<<256, 256, 0, stream>>>(W, coef);
    main_kernel<<<B_TOTAL / ROWS, THREADS, 0, stream>>>(
        x, (const bf16x8*)coef, theta, out);
}